// Round 10
// baseline (822.679 us; speedup 1.0000x reference)
//
#include <hip/hip_runtime.h>

// Problem constants (from reference)
#define N_NODES 16384
#define D_EMB   128
#define LIST_CAP 1024           // max common neighbors (max degree ~200 incl. i==j)
#define BM_U64   256            // u64 words per compressed row (2 KB)
#define FLAG_OFF N_NODES        // int idx: layout flag
#define CNT_OFF  (N_NODES + 1)  // int idx: used-row counter
#define LIST_OFF (N_NODES + 8)  // int idx: compacted used-row list [16384]
#define BM_OFF_BYTES (1 << 18)  // bitmaps start at 256 KiB into ws
#define WS_NEEDED (BM_OFF_BYTES + (size_t)N_NODES * (BM_U64 * 8)) // ~34 MB

// DIAGNOSTIC: amplify compress x6 (idempotent, rotated pair assignment) so
// the compress dispatch exceeds the harness's ~670us fillBuffer dispatches
// and becomes visible in the rocprof top-5 with its own counters.
#define AMP 6

// ---------------------------------------------------------------------------
// Pass 1: zero flags/counter; block 64 probes adjacency encoding.
__global__ __launch_bounds__(256) void zero_probe_kernel(
    const unsigned int* __restrict__ words, int* __restrict__ flags)
{
    if (blockIdx.x < 64) {
        flags[blockIdx.x * 256 + threadIdx.x] = 0;
    } else {
        __shared__ int s_any;
        if (threadIdx.x == 0) { s_any = 0; flags[CNT_OFF] = 0; }
        __syncthreads();
        int any = 0;
        for (int k = threadIdx.x; k < 16384; k += 256)
            if (words[k] > 1u) any = 1;
        if (any) atomicOr(&s_any, 1);
        __syncthreads();
        if (threadIdx.x == 0) flags[FLAG_OFF] = s_any;  // 1 => byte layout
    }
}

// Pass 2: dedup endpoints -> compacted used-row list (CAS winner appends).
__global__ __launch_bounds__(256) void mark_list_kernel(
    const int* __restrict__ links, int* __restrict__ flags, int n_endpoints)
{
    const int e = blockIdx.x * 256 + threadIdx.x;
    if (e >= n_endpoints) return;
    const int r = links[e];
    if (atomicCAS(&flags[r], 0, 1) == 0) {
        const int pos = atomicAdd(&flags[CNT_OFF], 1);
        flags[LIST_OFF + pos] = r;
    }
}

// Pass 3: compress two used rows per block, AMPLIFIED x AMP with rotated
// pair assignment (bijective per iteration -> full re-stream each iter,
// no block-local cache reuse; identical values written -> idempotent).
__global__ __launch_bounds__(256) void compress_pair_kernel(
    const void* __restrict__ adjv, const int* __restrict__ flags,
    unsigned long long* __restrict__ bm64)
{
    const int n_used = flags[CNT_OFF];
    const int npairs = (n_used + 1) >> 1;
    if (blockIdx.x >= npairs) return;
    const int t = threadIdx.x;
    const int byte_layout = flags[FLAG_OFF];

    for (int m = 0; m < AMP; ++m) {
        int p = (blockIdx.x + m * 2053) % npairs;
        const int i0 = 2 * p;
        const int i1 = i0 + 1;
        const int r0 = flags[LIST_OFF + i0];
        const int r1 = (i1 < n_used) ? flags[LIST_OFF + i1] : -1;

        if (!byte_layout) {
            const uint4* rowA = reinterpret_cast<const uint4*>(
                (const int*)adjv + (size_t)r0 * N_NODES);
            if (r1 >= 0) {
                const uint4* rowB = reinterpret_cast<const uint4*>(
                    (const int*)adjv + (size_t)r1 * N_NODES);
                unsigned int lo0 = 0u, hi0 = 0u, lo1 = 0u, hi1 = 0u;
#pragma unroll
                for (int k = 0; k < 8; ++k) {
                    const uint4 a = rowA[k * 256 + t];
                    const uint4 b = rowB[k * 256 + t];
                    lo0 |= (min(a.x,1u) | (min(a.y,1u)<<1) | (min(a.z,1u)<<2) | (min(a.w,1u)<<3)) << (4*k);
                    lo1 |= (min(b.x,1u) | (min(b.y,1u)<<1) | (min(b.z,1u)<<2) | (min(b.w,1u)<<3)) << (4*k);
                }
#pragma unroll
                for (int k = 8; k < 16; ++k) {
                    const uint4 a = rowA[k * 256 + t];
                    const uint4 b = rowB[k * 256 + t];
                    hi0 |= (min(a.x,1u) | (min(a.y,1u)<<1) | (min(a.z,1u)<<2) | (min(a.w,1u)<<3)) << (4*(k-8));
                    hi1 |= (min(b.x,1u) | (min(b.y,1u)<<1) | (min(b.z,1u)<<2) | (min(b.w,1u)<<3)) << (4*(k-8));
                }
                bm64[(size_t)r0 * BM_U64 + t] = ((unsigned long long)hi0 << 32) | lo0;
                bm64[(size_t)r1 * BM_U64 + t] = ((unsigned long long)hi1 << 32) | lo1;
            } else {
                unsigned int lo0 = 0u, hi0 = 0u;
#pragma unroll
                for (int k = 0; k < 8; ++k) {
                    const uint4 a = rowA[k * 256 + t];
                    lo0 |= (min(a.x,1u) | (min(a.y,1u)<<1) | (min(a.z,1u)<<2) | (min(a.w,1u)<<3)) << (4*k);
                }
#pragma unroll
                for (int k = 8; k < 16; ++k) {
                    const uint4 a = rowA[k * 256 + t];
                    hi0 |= (min(a.x,1u) | (min(a.y,1u)<<1) | (min(a.z,1u)<<2) | (min(a.w,1u)<<3)) << (4*(k-8));
                }
                bm64[(size_t)r0 * BM_U64 + t] = ((unsigned long long)hi0 << 32) | lo0;
            }
        } else {
            for (int s = 0; s < 2; ++s) {
                const int r = (s == 0) ? r0 : r1;
                if (r < 0) break;
                const uint4* row = reinterpret_cast<const uint4*>(
                    (const unsigned char*)adjv + (size_t)r * N_NODES);
                unsigned long long bits = 0ull;
#pragma unroll
                for (int q = 0; q < 4; ++q) {
                    const uint4 v = row[t * 4 + q];
                    const unsigned int arr[4] = {v.x, v.y, v.z, v.w};
#pragma unroll
                    for (int a = 0; a < 4; ++a)
#pragma unroll
                        for (int bb = 0; bb < 4; ++bb)
                            if ((arr[a] >> (8 * bb)) & 0xFFu)
                                bits |= 1ull << (q * 16 + a * 4 + bb);
                }
                bm64[(size_t)r * BM_U64 + t] = bits;
            }
        }
    }
}

// Pass 4: per link, one u64 AND per thread covers the whole row pair,
// decode set bits -> node indices, write [product(128) | cn_sum(128)].
__global__ __launch_bounds__(256) void link_kernel(
    const int* __restrict__ links, const unsigned long long* __restrict__ bm64,
    const float* __restrict__ emb, float* __restrict__ out,
    const int* __restrict__ flags, int n_links)
{
    const int link = blockIdx.x;
    if (link >= n_links) return;
    const int i = links[2 * link];
    const int j = links[2 * link + 1];
    const int byte_layout = flags[FLAG_OFF];

    __shared__ int s_list[LIST_CAP];
    __shared__ int s_count;
    if (threadIdx.x == 0) s_count = 0;
    __syncthreads();

    const int t = threadIdx.x;
    unsigned long long m = bm64[(size_t)i * BM_U64 + t]
                         & bm64[(size_t)j * BM_U64 + t];
    while (m) {
        const int b = __ffsll(m) - 1;
        m &= m - 1;
        const int node = byte_layout
            ? (t * 64 + b)
            : (((b >> 2) << 10) + (t << 2) + (b & 3));
        const int pos = atomicAdd(&s_count, 1);
        if (pos < LIST_CAP) s_list[pos] = node;
    }
    __syncthreads();

    int count = s_count;
    if (count > LIST_CAP) count = LIST_CAP;

    const size_t obase = (size_t)link * (2 * D_EMB);
    if (t < D_EMB) {
        out[obase + t] = emb[(size_t)i * D_EMB + t] * emb[(size_t)j * D_EMB + t];
    } else {
        const int d = t - D_EMB;
        float s = 0.0f;
        for (int c = 0; c < count; ++c)
            s += emb[(size_t)s_list[c] * D_EMB + d];
        out[obase + D_EMB + d] = s;
    }
}

// ---------------------------------------------------------------------------
// Fallback (ws too small): direct kernel — reads both full rows per link.
__global__ __launch_bounds__(256) void detect_layout_kernel(
    const unsigned int* __restrict__ words, int* __restrict__ flag)
{
    __shared__ int s_any;
    if (threadIdx.x == 0) s_any = 0;
    __syncthreads();
    int any = 0;
    for (int k = threadIdx.x; k < 16384; k += 256)
        if (words[k] > 1u) any = 1;
    if (any) atomicOr(&s_any, 1);
    __syncthreads();
    if (threadIdx.x == 0) *flag = s_any;
}

__global__ __launch_bounds__(256) void ncn_direct(
    const int* __restrict__ links, const void* __restrict__ adjv,
    const float* __restrict__ emb, float* __restrict__ out,
    const int* __restrict__ flag, int n_links)
{
    const int link = blockIdx.x;
    if (link >= n_links) return;
    const int i = links[2 * link];
    const int j = links[2 * link + 1];

    __shared__ int s_list[LIST_CAP];
    __shared__ int s_count;
    if (threadIdx.x == 0) s_count = 0;
    __syncthreads();

    const int byte_layout = flag ? flag[0] : 0;
    if (byte_layout) {
        const uint4* rowi = reinterpret_cast<const uint4*>(
            (const unsigned char*)adjv + (size_t)i * N_NODES);
        const uint4* rowj = reinterpret_cast<const uint4*>(
            (const unsigned char*)adjv + (size_t)j * N_NODES);
#pragma unroll
        for (int c = 0; c < 4; ++c) {
            const int idx = c * 256 + threadIdx.x;
            const uint4 a = rowi[idx];
            const uint4 bq = rowj[idx];
            unsigned int m[4] = {a.x & bq.x, a.y & bq.y, a.z & bq.z, a.w & bq.w};
            if (m[0] | m[1] | m[2] | m[3]) {
                const int base = idx * 16;
#pragma unroll
                for (int w = 0; w < 4; ++w) {
                    unsigned int v = m[w];
                    if (!v) continue;
#pragma unroll
                    for (int b8 = 0; b8 < 4; ++b8) {
                        if ((v >> (8 * b8)) & 0xFFu) {
                            int pos = atomicAdd(&s_count, 1);
                            if (pos < LIST_CAP) s_list[pos] = base + w * 4 + b8;
                        }
                    }
                }
            }
        }
    } else {
        const uint4* rowi = reinterpret_cast<const uint4*>(
            (const int*)adjv + (size_t)i * N_NODES);
        const uint4* rowj = reinterpret_cast<const uint4*>(
            (const int*)adjv + (size_t)j * N_NODES);
#pragma unroll
        for (int c = 0; c < 16; ++c) {
            const int idx = c * 256 + threadIdx.x;
            const uint4 a = rowi[idx];
            const uint4 bq = rowj[idx];
            const int base = idx * 4;
            if (a.x & bq.x) { int p = atomicAdd(&s_count, 1); if (p < LIST_CAP) s_list[p] = base + 0; }
            if (a.y & bq.y) { int p = atomicAdd(&s_count, 1); if (p < LIST_CAP) s_list[p] = base + 1; }
            if (a.z & bq.z) { int p = atomicAdd(&s_count, 1); if (p < LIST_CAP) s_list[p] = base + 2; }
            if (a.w & bq.w) { int p = atomicAdd(&s_count, 1); if (p < LIST_CAP) s_list[p] = base + 3; }
        }
    }
    __syncthreads();

    int count = s_count;
    if (count > LIST_CAP) count = LIST_CAP;

    const int t = threadIdx.x;
    const size_t obase = (size_t)link * (2 * D_EMB);
    if (t < D_EMB) {
        out[obase + t] = emb[(size_t)i * D_EMB + t] * emb[(size_t)j * D_EMB + t];
    } else {
        const int d = t - D_EMB;
        float s = 0.0f;
        for (int c = 0; c < count; ++c)
            s += emb[(size_t)s_list[c] * D_EMB + d];
        out[obase + D_EMB + d] = s;
    }
}

extern "C" void kernel_launch(void* const* d_in, const int* in_sizes, int n_in,
                              void* d_out, int out_size, void* d_ws, size_t ws_size,
                              hipStream_t stream) {
    const int* links = (const int*)d_in[0];     // int32 [n_links][2]
    const void* adj = d_in[1];                  // bool matrix (encoding probed)
    const float* emb = (const float*)d_in[2];   // fp32 [N_NODES][D_EMB]
    float* out = (float*)d_out;

    const int n_links = in_sizes[0] / 2;

    if (ws_size >= WS_NEEDED) {
        int* flags = (int*)d_ws;
        unsigned long long* bm64 =
            (unsigned long long*)((char*)d_ws + BM_OFF_BYTES);

        zero_probe_kernel<<<65, 256, 0, stream>>>(
            (const unsigned int*)adj, flags);
        mark_list_kernel<<<(2 * n_links + 255) / 256, 256, 0, stream>>>(
            links, flags, 2 * n_links);
        compress_pair_kernel<<<N_NODES / 2, 256, 0, stream>>>(
            adj, flags, bm64);
        link_kernel<<<n_links, 256, 0, stream>>>(
            links, bm64, emb, out, flags, n_links);
    } else {
        int* flag = (ws_size >= sizeof(int)) ? (int*)d_ws : nullptr;
        if (flag) detect_layout_kernel<<<1, 256, 0, stream>>>(
            (const unsigned int*)adj, flag);
        ncn_direct<<<n_links, 256, 0, stream>>>(links, adj, emb, out, flag, n_links);
    }
}

// Round 11
// 177.836 us; speedup vs baseline: 4.6261x; 4.6261x over previous
//
#include <hip/hip_runtime.h>

// Problem constants (from reference)
#define N_NODES 16384
#define D_EMB   128
#define LIST_CAP 1024           // max common neighbors (max degree ~200 incl. i==j)
#define BM_U64   256            // u64 words per compressed row (2 KB)
#define FLAG_OFF N_NODES        // int idx: layout flag
#define CNT_OFF  (N_NODES + 1)  // int idx: used-row counter
#define LIST_OFF (N_NODES + 8)  // int idx: compacted used-row list [16384]
#define BM_OFF_BYTES (1 << 18)  // bitmaps start at 256 KiB into ws
#define WS_NEEDED (BM_OFF_BYTES + (size_t)N_NODES * (BM_U64 * 8)) // ~34 MB
#define CGRID 16384             // compress grid (64-thread blocks)

// ---------------------------------------------------------------------------
// Pass 1: zero flags/counter; block 64 probes adjacency encoding.
// int32-bool: first 16384 u32 all in {0,1}; byte-bool: some word >1 w.p. ~1.
__global__ __launch_bounds__(256) void zero_probe_kernel(
    const unsigned int* __restrict__ words, int* __restrict__ flags)
{
    if (blockIdx.x < 64) {
        flags[blockIdx.x * 256 + threadIdx.x] = 0;
    } else {
        __shared__ int s_any;
        if (threadIdx.x == 0) { s_any = 0; flags[CNT_OFF] = 0; }
        __syncthreads();
        int any = 0;
        for (int k = threadIdx.x; k < 16384; k += 256)
            if (words[k] > 1u) any = 1;
        if (any) atomicOr(&s_any, 1);
        __syncthreads();
        if (threadIdx.x == 0) flags[FLAG_OFF] = s_any;  // 1 => byte layout
    }
}

// Pass 2: dedup endpoints -> compacted used-row list (CAS winner appends).
__global__ __launch_bounds__(256) void mark_list_kernel(
    const int* __restrict__ links, int* __restrict__ flags, int n_endpoints)
{
    const int e = blockIdx.x * 256 + threadIdx.x;
    if (e >= n_endpoints) return;
    const int r = links[e];
    if (atomicCAS(&flags[r], 0, 1) == 0) {
        const int pos = atomicAdd(&flags[CNT_OFF], 1);
        flags[LIST_OFF + pos] = r;
    }
}

// Pass 3: MANY-STREAMS compress. 64-thread (1-wave) blocks, grid-strided
// over quarter-row tasks (task = (row, quarter); 4 tasks/row). Every block
// works; ~24-32 independent streams/CU (R10 counters showed the old 256-thr
// dual-row version latency-bound: 32% HBM, 10% VALU, 44.6% occupancy).
// Thread t, load q (0..15): uint4 idx Q*1024 + q*64 + t -> 4 bits at b=4q+c.
// One u64 store per thread: word W = Q*64 + t.
// int32 PERMUTED layout: bit b of word W <-> node
//   (W>>6)*4096 + (b>>2)*256 + (W&63)*4 + (b&3).
// byte  PERMUTED layout: bit b of word W <-> node
//   (W>>6)*4096 + (b>>4)*1024 + (W&63)*16 + (b&15).
__global__ __launch_bounds__(64) void compress_tasks_kernel(
    const void* __restrict__ adjv, const int* __restrict__ flags,
    unsigned long long* __restrict__ bm64)
{
    const int n_used = flags[CNT_OFF];
    const int n_tasks = 4 * n_used;
    const int t = threadIdx.x;
    const int byte_layout = flags[FLAG_OFF];

    for (int task = blockIdx.x; task < n_tasks; task += CGRID) {
        const int r = flags[LIST_OFF + (task >> 2)];
        const int Q = task & 3;

        if (!byte_layout) {
            // quarter = 1024 uint4 (16 KB): 16 loads/thread, all independent.
            const uint4* qrow = reinterpret_cast<const uint4*>(
                (const int*)adjv + (size_t)r * N_NODES) + Q * 1024;
            unsigned int lo = 0u, hi = 0u;
#pragma unroll
            for (int q = 0; q < 8; ++q) {
                const uint4 v = qrow[q * 64 + t];
                const unsigned int nib = min(v.x,1u) | (min(v.y,1u)<<1)
                                       | (min(v.z,1u)<<2) | (min(v.w,1u)<<3);
                lo |= nib << (4 * q);
            }
#pragma unroll
            for (int q = 8; q < 16; ++q) {
                const uint4 v = qrow[q * 64 + t];
                const unsigned int nib = min(v.x,1u) | (min(v.y,1u)<<1)
                                       | (min(v.z,1u)<<2) | (min(v.w,1u)<<3);
                hi |= nib << (4 * (q - 8));
            }
            bm64[(size_t)r * BM_U64 + Q * 64 + t] =
                ((unsigned long long)hi << 32) | lo;
        } else {
            // byte quarter = 256 uint4 (4 KB): 4 loads/thread, 16 bits each.
            const uint4* qrow = reinterpret_cast<const uint4*>(
                (const unsigned char*)adjv + (size_t)r * N_NODES) + Q * 256;
            unsigned long long bits = 0ull;
#pragma unroll
            for (int q = 0; q < 4; ++q) {
                const uint4 v = qrow[q * 64 + t];
                const unsigned int arr[4] = {v.x, v.y, v.z, v.w};
                unsigned int half = 0;
#pragma unroll
                for (int a = 0; a < 4; ++a)
#pragma unroll
                    for (int bb = 0; bb < 4; ++bb)
                        half |= ((((arr[a] >> (8 * bb)) & 0xFFu) ? 1u : 0u)
                                 << (a * 4 + bb));
                bits |= (unsigned long long)half << (16 * q);
            }
            bm64[(size_t)r * BM_U64 + Q * 64 + t] = bits;
        }
    }
}

// Pass 4: per link, one u64 AND per thread covers the whole row pair,
// decode set bits -> node indices, write [product(128) | cn_sum(128)].
__global__ __launch_bounds__(256) void link_kernel(
    const int* __restrict__ links, const unsigned long long* __restrict__ bm64,
    const float* __restrict__ emb, float* __restrict__ out,
    const int* __restrict__ flags, int n_links)
{
    const int link = blockIdx.x;
    if (link >= n_links) return;
    const int i = links[2 * link];
    const int j = links[2 * link + 1];
    const int byte_layout = flags[FLAG_OFF];

    __shared__ int s_list[LIST_CAP];
    __shared__ int s_count;
    if (threadIdx.x == 0) s_count = 0;
    __syncthreads();

    const int t = threadIdx.x;                 // = word index W
    unsigned long long m = bm64[(size_t)i * BM_U64 + t]
                         & bm64[(size_t)j * BM_U64 + t];
    while (m) {
        const int b = __ffsll(m) - 1;
        m &= m - 1;
        const int node = byte_layout
            ? (((t >> 6) << 12) + ((b >> 4) << 10) + ((t & 63) << 4) + (b & 15))
            : (((t >> 6) << 12) + ((b >> 2) << 8) + ((t & 63) << 2) + (b & 3));
        const int pos = atomicAdd(&s_count, 1);
        if (pos < LIST_CAP) s_list[pos] = node;
    }
    __syncthreads();

    int count = s_count;
    if (count > LIST_CAP) count = LIST_CAP;

    const size_t obase = (size_t)link * (2 * D_EMB);
    if (t < D_EMB) {
        out[obase + t] = emb[(size_t)i * D_EMB + t] * emb[(size_t)j * D_EMB + t];
    } else {
        const int d = t - D_EMB;
        float s = 0.0f;
        for (int c = 0; c < count; ++c)
            s += emb[(size_t)s_list[c] * D_EMB + d];
        out[obase + D_EMB + d] = s;
    }
}

// ---------------------------------------------------------------------------
// Fallback (ws too small): direct kernel — reads both full rows per link.
__global__ __launch_bounds__(256) void detect_layout_kernel(
    const unsigned int* __restrict__ words, int* __restrict__ flag)
{
    __shared__ int s_any;
    if (threadIdx.x == 0) s_any = 0;
    __syncthreads();
    int any = 0;
    for (int k = threadIdx.x; k < 16384; k += 256)
        if (words[k] > 1u) any = 1;
    if (any) atomicOr(&s_any, 1);
    __syncthreads();
    if (threadIdx.x == 0) *flag = s_any;
}

__global__ __launch_bounds__(256) void ncn_direct(
    const int* __restrict__ links, const void* __restrict__ adjv,
    const float* __restrict__ emb, float* __restrict__ out,
    const int* __restrict__ flag, int n_links)
{
    const int link = blockIdx.x;
    if (link >= n_links) return;
    const int i = links[2 * link];
    const int j = links[2 * link + 1];

    __shared__ int s_list[LIST_CAP];
    __shared__ int s_count;
    if (threadIdx.x == 0) s_count = 0;
    __syncthreads();

    const int byte_layout = flag ? flag[0] : 0;
    if (byte_layout) {
        const uint4* rowi = reinterpret_cast<const uint4*>(
            (const unsigned char*)adjv + (size_t)i * N_NODES);
        const uint4* rowj = reinterpret_cast<const uint4*>(
            (const unsigned char*)adjv + (size_t)j * N_NODES);
#pragma unroll
        for (int c = 0; c < 4; ++c) {
            const int idx = c * 256 + threadIdx.x;
            const uint4 a = rowi[idx];
            const uint4 bq = rowj[idx];
            unsigned int m[4] = {a.x & bq.x, a.y & bq.y, a.z & bq.z, a.w & bq.w};
            if (m[0] | m[1] | m[2] | m[3]) {
                const int base = idx * 16;
#pragma unroll
                for (int w = 0; w < 4; ++w) {
                    unsigned int v = m[w];
                    if (!v) continue;
#pragma unroll
                    for (int b8 = 0; b8 < 4; ++b8) {
                        if ((v >> (8 * b8)) & 0xFFu) {
                            int pos = atomicAdd(&s_count, 1);
                            if (pos < LIST_CAP) s_list[pos] = base + w * 4 + b8;
                        }
                    }
                }
            }
        }
    } else {
        const uint4* rowi = reinterpret_cast<const uint4*>(
            (const int*)adjv + (size_t)i * N_NODES);
        const uint4* rowj = reinterpret_cast<const uint4*>(
            (const int*)adjv + (size_t)j * N_NODES);
#pragma unroll
        for (int c = 0; c < 16; ++c) {
            const int idx = c * 256 + threadIdx.x;
            const uint4 a = rowi[idx];
            const uint4 bq = rowj[idx];
            const int base = idx * 4;
            if (a.x & bq.x) { int p = atomicAdd(&s_count, 1); if (p < LIST_CAP) s_list[p] = base + 0; }
            if (a.y & bq.y) { int p = atomicAdd(&s_count, 1); if (p < LIST_CAP) s_list[p] = base + 1; }
            if (a.z & bq.z) { int p = atomicAdd(&s_count, 1); if (p < LIST_CAP) s_list[p] = base + 2; }
            if (a.w & bq.w) { int p = atomicAdd(&s_count, 1); if (p < LIST_CAP) s_list[p] = base + 3; }
        }
    }
    __syncthreads();

    int count = s_count;
    if (count > LIST_CAP) count = LIST_CAP;

    const int t = threadIdx.x;
    const size_t obase = (size_t)link * (2 * D_EMB);
    if (t < D_EMB) {
        out[obase + t] = emb[(size_t)i * D_EMB + t] * emb[(size_t)j * D_EMB + t];
    } else {
        const int d = t - D_EMB;
        float s = 0.0f;
        for (int c = 0; c < count; ++c)
            s += emb[(size_t)s_list[c] * D_EMB + d];
        out[obase + D_EMB + d] = s;
    }
}

extern "C" void kernel_launch(void* const* d_in, const int* in_sizes, int n_in,
                              void* d_out, int out_size, void* d_ws, size_t ws_size,
                              hipStream_t stream) {
    const int* links = (const int*)d_in[0];     // int32 [n_links][2]
    const void* adj = d_in[1];                  // bool matrix (encoding probed)
    const float* emb = (const float*)d_in[2];   // fp32 [N_NODES][D_EMB]
    float* out = (float*)d_out;

    const int n_links = in_sizes[0] / 2;

    if (ws_size >= WS_NEEDED) {
        int* flags = (int*)d_ws;
        unsigned long long* bm64 =
            (unsigned long long*)((char*)d_ws + BM_OFF_BYTES);

        zero_probe_kernel<<<65, 256, 0, stream>>>(
            (const unsigned int*)adj, flags);
        mark_list_kernel<<<(2 * n_links + 255) / 256, 256, 0, stream>>>(
            links, flags, 2 * n_links);
        compress_tasks_kernel<<<CGRID, 64, 0, stream>>>(
            adj, flags, bm64);
        link_kernel<<<n_links, 256, 0, stream>>>(
            links, bm64, emb, out, flags, n_links);
    } else {
        int* flag = (ws_size >= sizeof(int)) ? (int*)d_ws : nullptr;
        if (flag) detect_layout_kernel<<<1, 256, 0, stream>>>(
            (const unsigned int*)adj, flag);
        ncn_direct<<<n_links, 256, 0, stream>>>(links, adj, emb, out, flag, n_links);
    }
}